// Round 4
// baseline (551.563 us; speedup 1.0000x reference)
//
#include <hip/hip_runtime.h>

// OSQP batched ADMM, B=256 N=128 M=192, 400 iters.
// R9: R8 + quad-DPP all-gather to kill 16-way broadcast redundancy on the
// per-CU LDS pipe (R8's real bottleneck: 144 ds_read_b128/CU/iter ~ 1200cy,
// VALU idle at 38%). Quad lanes (bits 0-1 = rows, same qt) read DISJOINT
// 12-float chunks (3 b128/lane) and all-gather via 36 v_mov_dpp (quad_perm
// xor-1=0xB1, xor-2=0x4E) -> distribution runs on the idle VALU, 4x parallel
// per CU. Slot order [c, c^1, c^2, c^3] is used identically in the prologue
// V-build (same split+gather, slot-wise accumulate) so Vq and gathered-s
// align with no permutation. Reduce (shfl_xor 16/32), WT staging, double
// buffer, bitwise early exit, epilogue: unchanged from validated R8.
// Algebra: M = P + sI + rho*AtA (SPD);  Wt = A*Minv;  c = Minv q
//   V = A Minv At;  d = A c
//   iterate (s_0=0), state (p, s, Sacc):
//     r = V s ; w = r - d ; v = a*w + p ; z = med3(v,l,u) ;
//     s' = rho*(2z - v) ; Sacc' = (1-a)Sacc + a*s ; p' = v - a*z
//   epilogue: x = Wt^T Sacc - c

#define Nn 128
#define Mm 192
constexpr float RHO_    = 0.1f;
constexpr float SIGMA_  = 1e-6f;
constexpr float ALPHA_  = 1.6f;
constexpr int   NITERS_ = 400;

typedef float v2f __attribute__((ext_vector_type(2)));
typedef float v4f __attribute__((ext_vector_type(4)));

template<int CTRL>
__device__ __forceinline__ float dpp_movf(float x) {
  return __int_as_float(__builtin_amdgcn_update_dpp(
      __float_as_int(x), __float_as_int(x), CTRL, 0xF, 0xF, false));
}
template<int CTRL>
__device__ __forceinline__ v4f dpp_mov4(v4f x) {
  v4f r;
  r.x = dpp_movf<CTRL>(x.x);
  r.y = dpp_movf<CTRL>(x.y);
  r.z = dpp_movf<CTRL>(x.z);
  r.w = dpp_movf<CTRL>(x.w);
  return r;
}

//======================= Kernel 1: precompute WtT, c ===============================
// [R3-validated GJ core, unchanged]
template<int K0>
__device__ __forceinline__ void gj_block(float rr[32], float* __restrict__ buf0,
                                         float* __restrict__ buf1,
                                         const int irow, const int qq) {
  const bool qsel = (qq == K0);
  #pragma unroll
  for (int kk = 0; kk < 32; kk++) {
    const int k = 32*K0 + kk;
    float* wb = ((kk & 1) == 0) ? buf0 : buf1;
    if (irow == k) {
      #pragma unroll
      for (int j4 = 0; j4 < 8; j4++)
        *(float4*)&wb[36*qq + 4*j4] = *(const float4*)&rr[4*j4];
    }
    __syncthreads();
    const float akk  = wb[36*K0 + kk];
    float pinv = __builtin_amdgcn_rcpf(akk);
    pinv = pinv + pinv*(1.0f - akk*pinv);
    constexpr int QP = K0 | (K0<<2) | (K0<<4) | (K0<<6);
    const int fi = __builtin_amdgcn_update_dpp(__float_as_int(rr[kk]),
                      __float_as_int(rr[kk]), QP, 0xF, 0xF, false);
    const float f = __int_as_float(fi);
    const bool piv = (irow == k);
    float gfac = f * pinv;
    gfac = piv ? (1.0f - pinv) : gfac;
    float rk[32];
    #pragma unroll
    for (int j4 = 0; j4 < 8; j4++)
      *(float4*)&rk[4*j4] = *(const float4*)&wb[36*qq + 4*j4];
    #pragma unroll
    for (int j = 0; j < 32; j++) rr[j] -= gfac * rk[j];
    const float pivfix = piv ? pinv : -gfac;
    if (qsel) rr[kk] = pivfix;
  }
}

__global__ void __launch_bounds__(512, 2)
precompute_kernel(const float* __restrict__ Pg, const float* __restrict__ qg,
                  const float* __restrict__ Ag, float* __restrict__ wsWt,
                  float* __restrict__ wsC)
{
  __shared__ float smem[16384];
  const int t = threadIdx.x;
  const int b = blockIdx.x;
  const float* __restrict__ Pb = Pg + (size_t)b*Nn*Nn;
  const float* __restrict__ qb = qg + (size_t)b*Nn;
  const float* __restrict__ Ab = Ag + (size_t)b*Mm*Nn;

  //---- Phase A: S = P + sigma*I + rho * A^T A ----
  {
    const int ar = t & 31;
    const int bc = t >> 5;
    float acc[4][8];
    #pragma unroll
    for (int a=0;a<4;a++)
      #pragma unroll
      for (int j=0;j<8;j++) acc[a][j]=0.f;

    for (int c=0;c<6;c++) {
      __syncthreads();
      {
        const float4* src = (const float4*)(Ab + c*32*Nn);
        float4* dst = (float4*)smem;
        dst[t]     = src[t];
        dst[t+512] = src[t+512];
      }
      __syncthreads();
      #pragma unroll 2
      for (int m=0;m<32;m++) {
        const float4 ra  = *(const float4*)&smem[m*Nn + 4*ar];
        const float4 cb0 = *(const float4*)&smem[m*Nn + 8*bc];
        const float4 cb1 = *(const float4*)&smem[m*Nn + 8*bc + 4];
        const float rv[4] = {ra.x, ra.y, ra.z, ra.w};
        const float cv[8] = {cb0.x,cb0.y,cb0.z,cb0.w,cb1.x,cb1.y,cb1.z,cb1.w};
        #pragma unroll
        for (int a=0;a<4;a++)
          #pragma unroll
          for (int j=0;j<8;j++) acc[a][j] += rv[a]*cv[j];
      }
    }
    __syncthreads();
    #pragma unroll
    for (int a=0;a<4;a++) {
      const int i = 4*ar + a;
      #pragma unroll
      for (int j=0;j<8;j++) {
        const int jj = 8*bc + j;
        float v = Pb[i*Nn + jj] + RHO_*acc[a][j];
        if (i == jj) v += SIGMA_;
        smem[i*Nn + jj] = v;
      }
    }
    __syncthreads();
  }

  //---- Phase B: Gauss-Jordan inverse ----
  {
    const int irow = t >> 2;
    const int qq   = t & 3;
    float rr[32];
    #pragma unroll
    for (int j=0;j<32;j++) rr[j] = smem[irow*Nn + 32*qq + j];
    __syncthreads();
    float* buf0 = smem;
    float* buf1 = smem + 144;
    gj_block<0>(rr, buf0, buf1, irow, qq);
    gj_block<1>(rr, buf0, buf1, irow, qq);
    gj_block<2>(rr, buf0, buf1, irow, qq);
    gj_block<3>(rr, buf0, buf1, irow, qq);
    __syncthreads();
    #pragma unroll
    for (int j=0;j<32;j++) smem[irow*Nn + 32*qq + j] = rr[j];
  }
  __syncthreads();

  //---- Phase C: WtT[k][j] = (A*Minv)[j][k] -> wsWt (transposed!); c = Minv q ----
  {
    const int jr = t & 63, kc = t >> 6;
    v2f acc[3][8];
    #pragma unroll
    for (int a=0;a<3;a++)
      #pragma unroll
      for (int p=0;p<8;p++) acc[a][p] = (v2f){0.f,0.f};

    for (int mi=0; mi<32; mi++) {
      const v4f a0 = *(const v4f*)&Ab[(jr      )*Nn + 4*mi];
      const v4f a1 = *(const v4f*)&Ab[(jr +  64)*Nn + 4*mi];
      const v4f a2 = *(const v4f*)&Ab[(jr + 128)*Nn + 4*mi];
      const float am[3][4] = {{a0.x,a0.y,a0.z,a0.w},
                              {a1.x,a1.y,a1.z,a1.w},
                              {a2.x,a2.y,a2.z,a2.w}};
      #pragma unroll
      for (int q=0;q<4;q++) {
        const int m = 4*mi + q;
        const v4f w0 = *(const v4f*)&smem[m*Nn + 16*kc +  0];
        const v4f w1 = *(const v4f*)&smem[m*Nn + 16*kc +  4];
        const v4f w2 = *(const v4f*)&smem[m*Nn + 16*kc +  8];
        const v4f w3 = *(const v4f*)&smem[m*Nn + 16*kc + 12];
        const v2f wp[8] = {(v2f){w0.x,w0.y},(v2f){w0.z,w0.w},
                           (v2f){w1.x,w1.y},(v2f){w1.z,w1.w},
                           (v2f){w2.x,w2.y},(v2f){w2.z,w2.w},
                           (v2f){w3.x,w3.y},(v2f){w3.z,w3.w}};
        #pragma unroll
        for (int a=0;a<3;a++) {
          const v2f amv = (v2f){am[a][q], am[a][q]};
          #pragma unroll
          for (int p=0;p<8;p++) acc[a][p] += amv * wp[p];
        }
      }
    }
    // transposed store: WtT[col][j], lanes (jr) run along j -> coalesced
    float* wb = wsWt + (size_t)b*Nn*Mm;
    #pragma unroll
    for (int a=0;a<3;a++) {
      const int j = jr + 64*a;
      #pragma unroll
      for (int p=0;p<8;p++) {
        const int col = 16*kc + 2*p;
        wb[(size_t)(col    )*Mm + j] = acc[a][p].x;
        wb[(size_t)(col + 1)*Mm + j] = acc[a][p].y;
      }
    }
  }
  if (t < Nn) {
    float cc = 0.f;
    #pragma unroll 4
    for (int k=0;k<Nn;k++) cc += smem[k*Nn + t] * qb[k];
    wsC[(size_t)b*Nn + t] = cc;
  }
}

//======================= Kernel 2: quarter-row V-space ADMM loop ===================
#define WT_LD 196                       // padded LDS row stride (floats), 16B-aligned
#define OFF_S0   (Nn*WT_LD)             // 25088
#define OFF_S1   (OFF_S0 + Mm)          // 25280
#define OFF_SACC (OFF_S1 + Mm)          // 25472
#define OFF_C    (OFF_SACC + Mm)        // 25664
#define OFF_FLAG (OFF_C + Nn)           // 25792
#define LOOP_LDS_FLOATS (OFF_FLAG + 2)  // 25794 floats = 103176 B

// 768 threads = 12 waves = 3 waves/EU. Per-lane: Vq 48 + gather temps 48 +
// working ~25 ~= 120 VGPR < 170 budget at 3 waves/EU -> no spill.
__global__ __launch_bounds__(768, 3) void
loop_kernel(const float* __restrict__ Ag, const float* __restrict__ lg,
            const float* __restrict__ ug, const float* __restrict__ wsWtT,
            const float* __restrict__ wsC, float* __restrict__ outg)
{
  extern __shared__ float smem[];
  const int t = threadIdx.x, b = blockIdx.x;
  const int qt  = (t >> 4) & 3;                // quarter 0..3 (s-cols 48qt..48qt+47)
  const int j   = ((t >> 6) << 4) | (t & 15);  // row 0..191 (wave w owns rows 16w..16w+15)
  const int ch0 = t & 3;                       // this lane's read-chunk within quarter
  const bool wlane = (qt == 0);
  const float* __restrict__ Wg = wsWtT + (size_t)b*Nn*Mm;   // [128][192]
  const float* __restrict__ cb = wsC  + (size_t)b*Nn;
  const float* __restrict__ Ab = Ag   + (size_t)b*Mm*Nn;

  float* WT    = smem;                 // [128][196]
  float* sT0   = smem + OFF_S0;
  float* sT1   = smem + OFF_S1;
  float* sacc  = smem + OFF_SACC;
  float* c_s   = smem + OFF_C;
  float* sflag = smem + OFF_FLAG;

  // ---- stage WtT into LDS: thread covers col jc for 32 rows (coalesced both sides)
  {
    const int jc = t % 192;
    const int g  = t / 192;              // 0..3
    #pragma unroll 4
    for (int i = 0; i < 32; i++) {
      const int k = 32*g + i;
      WT[k*WT_LD + jc] = Wg[(size_t)k*Mm + jc];
    }
  }
  if (t < Nn) c_s[t] = cb[t];
  if (t < Mm) sT0[t] = 0.f;
  if (t < 2) sflag[t] = 0.f;
  __syncthreads();

  // ---- bounds (all 4 quarter-lanes load same value: broadcast) ----
  const float lreg = lg[(size_t)b*Mm + j];
  const float ureg = ug[(size_t)b*Mm + j];
  const float* Arow = Ab + (size_t)j*Nn;

  // ---- d = A_j . c  (quarter partial over k in [32qt,32qt+32), shfl-combined) ----
  float dreg;
  {
    float dp = 0.f;
    const float4* ar = (const float4*)(Arow + 32*qt);
    const float4* cr = (const float4*)(c_s + 32*qt);
    #pragma unroll
    for (int k4 = 0; k4 < 8; k4++) {
      const float4 av = ar[k4], cv = cr[k4];
      dp += av.x*cv.x + av.y*cv.y + av.z*cv.z + av.w*cv.w;
    }
    const float d1 = dp + __shfl_xor(dp, 16, 64);
    dreg = d1 + __shfl_xor(d1, 32, 64);   // bitwise-identical in all 4 quarter lanes
  }

  // ---- V quarter in slot order [c, c^1, c^2, c^3]:
  //   Vq[6u..6u+5] = V[j][48qt + 12*(ch0^u) .. +12)
  // built with the SAME chunk-split + quad-DPP gather as the iter s-read, so
  // slots align automatically.
  v2f Vq[24];
  #pragma unroll
  for (int p = 0; p < 24; p++) Vq[p] = (v2f){0.f, 0.f};
  for (int m = 0; m < 32; m++) {
    const v4f a4 = *(const v4f*)&Arow[4*m];
    const float aks[4] = {a4.x, a4.y, a4.z, a4.w};
    #pragma unroll
    for (int kk = 0; kk < 4; kk++) {
      const v2f av = (v2f){aks[kk], aks[kk]};
      const float* wp = &WT[(4*m + kk)*WT_LD + 48*qt + 12*ch0];
      const v4f m0 = *(const v4f*)&wp[0];
      const v4f m1 = *(const v4f*)&wp[4];
      const v4f m2 = *(const v4f*)&wp[8];
      const v4f n0 = dpp_mov4<0xB1>(m0);
      const v4f n1 = dpp_mov4<0xB1>(m1);
      const v4f n2 = dpp_mov4<0xB1>(m2);
      const v4f p0 = dpp_mov4<0x4E>(m0);
      const v4f p1 = dpp_mov4<0x4E>(m1);
      const v4f p2 = dpp_mov4<0x4E>(m2);
      const v4f q0 = dpp_mov4<0x4E>(n0);
      const v4f q1 = dpp_mov4<0x4E>(n1);
      const v4f q2 = dpp_mov4<0x4E>(n2);
      Vq[ 0] = __builtin_elementwise_fma(av, (v2f){m0.x,m0.y}, Vq[ 0]);
      Vq[ 1] = __builtin_elementwise_fma(av, (v2f){m0.z,m0.w}, Vq[ 1]);
      Vq[ 2] = __builtin_elementwise_fma(av, (v2f){m1.x,m1.y}, Vq[ 2]);
      Vq[ 3] = __builtin_elementwise_fma(av, (v2f){m1.z,m1.w}, Vq[ 3]);
      Vq[ 4] = __builtin_elementwise_fma(av, (v2f){m2.x,m2.y}, Vq[ 4]);
      Vq[ 5] = __builtin_elementwise_fma(av, (v2f){m2.z,m2.w}, Vq[ 5]);
      Vq[ 6] = __builtin_elementwise_fma(av, (v2f){n0.x,n0.y}, Vq[ 6]);
      Vq[ 7] = __builtin_elementwise_fma(av, (v2f){n0.z,n0.w}, Vq[ 7]);
      Vq[ 8] = __builtin_elementwise_fma(av, (v2f){n1.x,n1.y}, Vq[ 8]);
      Vq[ 9] = __builtin_elementwise_fma(av, (v2f){n1.z,n1.w}, Vq[ 9]);
      Vq[10] = __builtin_elementwise_fma(av, (v2f){n2.x,n2.y}, Vq[10]);
      Vq[11] = __builtin_elementwise_fma(av, (v2f){n2.z,n2.w}, Vq[11]);
      Vq[12] = __builtin_elementwise_fma(av, (v2f){p0.x,p0.y}, Vq[12]);
      Vq[13] = __builtin_elementwise_fma(av, (v2f){p0.z,p0.w}, Vq[13]);
      Vq[14] = __builtin_elementwise_fma(av, (v2f){p1.x,p1.y}, Vq[14]);
      Vq[15] = __builtin_elementwise_fma(av, (v2f){p1.z,p1.w}, Vq[15]);
      Vq[16] = __builtin_elementwise_fma(av, (v2f){p2.x,p2.y}, Vq[16]);
      Vq[17] = __builtin_elementwise_fma(av, (v2f){p2.z,p2.w}, Vq[17]);
      Vq[18] = __builtin_elementwise_fma(av, (v2f){q0.x,q0.y}, Vq[18]);
      Vq[19] = __builtin_elementwise_fma(av, (v2f){q0.z,q0.w}, Vq[19]);
      Vq[20] = __builtin_elementwise_fma(av, (v2f){q1.x,q1.y}, Vq[20]);
      Vq[21] = __builtin_elementwise_fma(av, (v2f){q1.z,q1.w}, Vq[21]);
      Vq[22] = __builtin_elementwise_fma(av, (v2f){q2.x,q2.y}, Vq[22]);
      Vq[23] = __builtin_elementwise_fma(av, (v2f){q2.z,q2.w}, Vq[23]);
    }
  }

  float sreg = 0.f, preg = 0.f, Sacc = 0.f;
  bool cvg = false;

  // per iter/lane: 3 ds_read_b128 (disjoint chunks) + 36 v_mov_dpp gather +
  // 24 v_pk_fma + 2 shfl_xor + chain. One barrier.
#define ITER(RD, WR, CHK, PH)                                                  \
  {                                                                            \
    const float* rp = (RD) + 48*qt + 12*ch0;                                   \
    const v4f m0 = *(const v4f*)&rp[0];                                        \
    const v4f m1 = *(const v4f*)&rp[4];                                        \
    const v4f m2 = *(const v4f*)&rp[8];                                        \
    const v4f n0 = dpp_mov4<0xB1>(m0);                                         \
    const v4f n1 = dpp_mov4<0xB1>(m1);                                         \
    const v4f n2 = dpp_mov4<0xB1>(m2);                                         \
    const v4f p0 = dpp_mov4<0x4E>(m0);                                         \
    const v4f p1 = dpp_mov4<0x4E>(m1);                                         \
    const v4f p2 = dpp_mov4<0x4E>(m2);                                         \
    const v4f q0 = dpp_mov4<0x4E>(n0);                                         \
    const v4f q1 = dpp_mov4<0x4E>(n1);                                         \
    const v4f q2 = dpp_mov4<0x4E>(n2);                                         \
    v2f a0=(v2f){0.f,0.f}, a1=(v2f){0.f,0.f};                                  \
    v2f a2=(v2f){0.f,0.f}, a3=(v2f){0.f,0.f};                                  \
    a0 = __builtin_elementwise_fma(Vq[ 0], (v2f){m0.x,m0.y}, a0);              \
    a1 = __builtin_elementwise_fma(Vq[ 1], (v2f){m0.z,m0.w}, a1);              \
    a2 = __builtin_elementwise_fma(Vq[ 2], (v2f){m1.x,m1.y}, a2);              \
    a3 = __builtin_elementwise_fma(Vq[ 3], (v2f){m1.z,m1.w}, a3);              \
    a0 = __builtin_elementwise_fma(Vq[ 4], (v2f){m2.x,m2.y}, a0);              \
    a1 = __builtin_elementwise_fma(Vq[ 5], (v2f){m2.z,m2.w}, a1);              \
    a2 = __builtin_elementwise_fma(Vq[ 6], (v2f){n0.x,n0.y}, a2);              \
    a3 = __builtin_elementwise_fma(Vq[ 7], (v2f){n0.z,n0.w}, a3);              \
    a0 = __builtin_elementwise_fma(Vq[ 8], (v2f){n1.x,n1.y}, a0);              \
    a1 = __builtin_elementwise_fma(Vq[ 9], (v2f){n1.z,n1.w}, a1);              \
    a2 = __builtin_elementwise_fma(Vq[10], (v2f){n2.x,n2.y}, a2);              \
    a3 = __builtin_elementwise_fma(Vq[11], (v2f){n2.z,n2.w}, a3);              \
    a0 = __builtin_elementwise_fma(Vq[12], (v2f){p0.x,p0.y}, a0);              \
    a1 = __builtin_elementwise_fma(Vq[13], (v2f){p0.z,p0.w}, a1);              \
    a2 = __builtin_elementwise_fma(Vq[14], (v2f){p1.x,p1.y}, a2);              \
    a3 = __builtin_elementwise_fma(Vq[15], (v2f){p1.z,p1.w}, a3);              \
    a0 = __builtin_elementwise_fma(Vq[16], (v2f){p2.x,p2.y}, a0);              \
    a1 = __builtin_elementwise_fma(Vq[17], (v2f){p2.z,p2.w}, a1);              \
    a2 = __builtin_elementwise_fma(Vq[18], (v2f){q0.x,q0.y}, a2);              \
    a3 = __builtin_elementwise_fma(Vq[19], (v2f){q0.z,q0.w}, a3);              \
    a0 = __builtin_elementwise_fma(Vq[20], (v2f){q1.x,q1.y}, a0);              \
    a1 = __builtin_elementwise_fma(Vq[21], (v2f){q1.z,q1.w}, a1);              \
    a2 = __builtin_elementwise_fma(Vq[22], (v2f){q2.x,q2.y}, a2);              \
    a3 = __builtin_elementwise_fma(Vq[23], (v2f){q2.z,q2.w}, a3);              \
    a0 += a1; a2 += a3; a0 += a2;                                              \
    const float part = a0.x + a0.y;                                            \
    const float r1 = part + __shfl_xor(part, 16, 64);                          \
    const float r  = r1 + __shfl_xor(r1, 32, 64);                              \
    const float w  = r - dreg;                                                 \
    const float v  = fmaf(ALPHA_, w, preg);                                    \
    const float z  = __builtin_amdgcn_fmed3f(v, lreg, ureg);                   \
    const float sn = RHO_ * fmaf(2.0f, z, -v);                                 \
    const float pn = fmaf(-ALPHA_, z, v);                                      \
    if (wlane) (WR)[j] = sn;                                                   \
    if (CHK) { if (wlane && !(sn == sreg && pn == preg)) sflag[PH] = 1.f; }    \
    Sacc = fmaf(1.0f - ALPHA_, Sacc, ALPHA_ * sreg);                           \
    sreg = sn; preg = pn;                                                      \
    if ((CHK) && t == 0) sflag[(PH) ^ 1] = 0.f;                                \
    __syncthreads();                                                           \
    if (CHK) cvg = (sflag[PH] == 0.f);                                         \
  }

  #pragma unroll 1
  for (int it2 = 0; it2 < NITERS_/2; it2++) {
    ITER(sT0, sT1, false, 0)
    const bool chk = ((it2 & 3) == 3) && (it2 < NITERS_/2 - 40);
    const int ph = (it2 >> 2) & 1;
    ITER(sT1, sT0, chk, ph)
    if (cvg) break;   // bitwise fixed point: remaining iterations are identities
  }
#undef ITER
  if (cvg) Sacc = sreg;   // Sacc -> s* geometrically; |(-0.6)^80| ~ 2e-18

  // ---- epilogue: x = Wt^T Sacc - c  (= WtT rows . Sacc) ----
  if (wlane) sacc[j] = Sacc;
  __syncthreads();
  if (t < Nn) {
    const float* wr = &WT[t*WT_LD];
    v2f xa = (v2f){0.f,0.f}, xb = (v2f){0.f,0.f};
    #pragma unroll
    for (int j4 = 0; j4 < 48; j4++) {
      const v4f wv = *(const v4f*)&wr[4*j4];
      const v4f sv = *(const v4f*)&sacc[4*j4];
      xa = __builtin_elementwise_fma((v2f){wv.x,wv.y}, (v2f){sv.x,sv.y}, xa);
      xb = __builtin_elementwise_fma((v2f){wv.z,wv.w}, (v2f){sv.z,sv.w}, xb);
    }
    xa += xb;
    outg[(size_t)b*Nn + t] = xa.x + xa.y - c_s[t];
  }
}

extern "C" void kernel_launch(void* const* d_in, const int* in_sizes, int n_in,
                              void* d_out, int out_size, void* d_ws, size_t ws_size,
                              hipStream_t stream) {
  const float* P = (const float*)d_in[0];
  const float* q = (const float*)d_in[1];
  const float* A = (const float*)d_in[2];
  const float* l = (const float*)d_in[3];
  const float* u = (const float*)d_in[4];
  (void)in_sizes; (void)n_in; (void)out_size; (void)ws_size;
  float* wsWt = (float*)d_ws;                      // WtT: 256*128*192 floats = 25.2 MB
  float* wsC  = wsWt + (size_t)256*Mm*Nn;          // 256*128 floats
  precompute_kernel<<<256, 512, 0, stream>>>(P, q, A, wsWt, wsC);
  loop_kernel<<<256, 768, LOOP_LDS_FLOATS*4, stream>>>(A, l, u, wsWt, wsC, (float*)d_out);
}

// Round 5
// 404.051 us; speedup vs baseline: 1.3651x; 1.3651x over previous
//
#include <hip/hip_runtime.h>

// OSQP batched ADMM, B=256 N=128 M=192, 400 iters.
// R10: row-sharing. R8 was LDS-instruction-bound (144 broadcast ds_read_b128
// /CU/iter ~1200cy; VALU idle). R9's DPP gather regressed (wrong trade: 36
// VALU movs to save 9 LDS instrs). R10 amortizes each s-read across THREE
// V-rows: 512 thr (8 waves, 2/SIMD), lane owns rows (j0, j0+64, j0+128) at
// s-cols [24e,24e+24), Ve[3][12 v2f]=72 VGPR (fits, no spill). Per iter:
// 6 ds_read_b128 + 36 pk_fma + 9 dpp_add (xor1/xor2 quad + xor8 row_ror:8,
// pure VALU reduce replaces ds_bpermute shfl) + 1 combined masked write
// (lane e<3 writes row j0+64e). LDS instr 168 -> 56 per CU-iter. s-buffers
// padded to 36-float slots so the 8 chunk-lines cover all 32 banks: 0 conflict.
// Algebra: M = P + sI + rho*AtA (SPD);  Wt = A*Minv;  c = Minv q
//   V = A Minv At;  d = A c
//   iterate (s_0=0), state (p, s, Sacc):
//     r = V s ; w = r - d ; v = a*w + p ; z = med3(v,l,u) ;
//     s' = rho*(2z - v) ; Sacc' = (1-a)Sacc + a*s ; p' = v - a*z
//   epilogue: x = Wt^T Sacc - c

#define Nn 128
#define Mm 192
constexpr float RHO_    = 0.1f;
constexpr float SIGMA_  = 1e-6f;
constexpr float ALPHA_  = 1.6f;
constexpr int   NITERS_ = 400;

typedef float v2f __attribute__((ext_vector_type(2)));
typedef float v4f __attribute__((ext_vector_type(4)));

template<int CTRL>
__device__ __forceinline__ float dpp_add(float x) {
  // old = x so GCNDPPCombine folds to v_add_f32_dpp
  int y = __builtin_amdgcn_update_dpp(__float_as_int(x), __float_as_int(x),
                                      CTRL, 0xF, 0xF, false);
  return x + __int_as_float(y);
}

//======================= Kernel 1: precompute WtT, c ===============================
// [R3-validated GJ core, unchanged]
template<int K0>
__device__ __forceinline__ void gj_block(float rr[32], float* __restrict__ buf0,
                                         float* __restrict__ buf1,
                                         const int irow, const int qq) {
  const bool qsel = (qq == K0);
  #pragma unroll
  for (int kk = 0; kk < 32; kk++) {
    const int k = 32*K0 + kk;
    float* wb = ((kk & 1) == 0) ? buf0 : buf1;
    if (irow == k) {
      #pragma unroll
      for (int j4 = 0; j4 < 8; j4++)
        *(float4*)&wb[36*qq + 4*j4] = *(const float4*)&rr[4*j4];
    }
    __syncthreads();
    const float akk  = wb[36*K0 + kk];
    float pinv = __builtin_amdgcn_rcpf(akk);
    pinv = pinv + pinv*(1.0f - akk*pinv);
    constexpr int QP = K0 | (K0<<2) | (K0<<4) | (K0<<6);
    const int fi = __builtin_amdgcn_update_dpp(__float_as_int(rr[kk]),
                      __float_as_int(rr[kk]), QP, 0xF, 0xF, false);
    const float f = __int_as_float(fi);
    const bool piv = (irow == k);
    float gfac = f * pinv;
    gfac = piv ? (1.0f - pinv) : gfac;
    float rk[32];
    #pragma unroll
    for (int j4 = 0; j4 < 8; j4++)
      *(float4*)&rk[4*j4] = *(const float4*)&wb[36*qq + 4*j4];
    #pragma unroll
    for (int j = 0; j < 32; j++) rr[j] -= gfac * rk[j];
    const float pivfix = piv ? pinv : -gfac;
    if (qsel) rr[kk] = pivfix;
  }
}

__global__ void __launch_bounds__(512, 2)
precompute_kernel(const float* __restrict__ Pg, const float* __restrict__ qg,
                  const float* __restrict__ Ag, float* __restrict__ wsWt,
                  float* __restrict__ wsC)
{
  __shared__ float smem[16384];
  const int t = threadIdx.x;
  const int b = blockIdx.x;
  const float* __restrict__ Pb = Pg + (size_t)b*Nn*Nn;
  const float* __restrict__ qb = qg + (size_t)b*Nn;
  const float* __restrict__ Ab = Ag + (size_t)b*Mm*Nn;

  //---- Phase A: S = P + sigma*I + rho * A^T A ----
  {
    const int ar = t & 31;
    const int bc = t >> 5;
    float acc[4][8];
    #pragma unroll
    for (int a=0;a<4;a++)
      #pragma unroll
      for (int j=0;j<8;j++) acc[a][j]=0.f;

    for (int c=0;c<6;c++) {
      __syncthreads();
      {
        const float4* src = (const float4*)(Ab + c*32*Nn);
        float4* dst = (float4*)smem;
        dst[t]     = src[t];
        dst[t+512] = src[t+512];
      }
      __syncthreads();
      #pragma unroll 2
      for (int m=0;m<32;m++) {
        const float4 ra  = *(const float4*)&smem[m*Nn + 4*ar];
        const float4 cb0 = *(const float4*)&smem[m*Nn + 8*bc];
        const float4 cb1 = *(const float4*)&smem[m*Nn + 8*bc + 4];
        const float rv[4] = {ra.x, ra.y, ra.z, ra.w};
        const float cv[8] = {cb0.x,cb0.y,cb0.z,cb0.w,cb1.x,cb1.y,cb1.z,cb1.w};
        #pragma unroll
        for (int a=0;a<4;a++)
          #pragma unroll
          for (int j=0;j<8;j++) acc[a][j] += rv[a]*cv[j];
      }
    }
    __syncthreads();
    #pragma unroll
    for (int a=0;a<4;a++) {
      const int i = 4*ar + a;
      #pragma unroll
      for (int j=0;j<8;j++) {
        const int jj = 8*bc + j;
        float v = Pb[i*Nn + jj] + RHO_*acc[a][j];
        if (i == jj) v += SIGMA_;
        smem[i*Nn + jj] = v;
      }
    }
    __syncthreads();
  }

  //---- Phase B: Gauss-Jordan inverse ----
  {
    const int irow = t >> 2;
    const int qq   = t & 3;
    float rr[32];
    #pragma unroll
    for (int j=0;j<32;j++) rr[j] = smem[irow*Nn + 32*qq + j];
    __syncthreads();
    float* buf0 = smem;
    float* buf1 = smem + 144;
    gj_block<0>(rr, buf0, buf1, irow, qq);
    gj_block<1>(rr, buf0, buf1, irow, qq);
    gj_block<2>(rr, buf0, buf1, irow, qq);
    gj_block<3>(rr, buf0, buf1, irow, qq);
    __syncthreads();
    #pragma unroll
    for (int j=0;j<32;j++) smem[irow*Nn + 32*qq + j] = rr[j];
  }
  __syncthreads();

  //---- Phase C: WtT[k][j] = (A*Minv)[j][k] -> wsWt (transposed!); c = Minv q ----
  {
    const int jr = t & 63, kc = t >> 6;
    v2f acc[3][8];
    #pragma unroll
    for (int a=0;a<3;a++)
      #pragma unroll
      for (int p=0;p<8;p++) acc[a][p] = (v2f){0.f,0.f};

    for (int mi=0; mi<32; mi++) {
      const v4f a0 = *(const v4f*)&Ab[(jr      )*Nn + 4*mi];
      const v4f a1 = *(const v4f*)&Ab[(jr +  64)*Nn + 4*mi];
      const v4f a2 = *(const v4f*)&Ab[(jr + 128)*Nn + 4*mi];
      const float am[3][4] = {{a0.x,a0.y,a0.z,a0.w},
                              {a1.x,a1.y,a1.z,a1.w},
                              {a2.x,a2.y,a2.z,a2.w}};
      #pragma unroll
      for (int q=0;q<4;q++) {
        const int m = 4*mi + q;
        const v4f w0 = *(const v4f*)&smem[m*Nn + 16*kc +  0];
        const v4f w1 = *(const v4f*)&smem[m*Nn + 16*kc +  4];
        const v4f w2 = *(const v4f*)&smem[m*Nn + 16*kc +  8];
        const v4f w3 = *(const v4f*)&smem[m*Nn + 16*kc + 12];
        const v2f wp[8] = {(v2f){w0.x,w0.y},(v2f){w0.z,w0.w},
                           (v2f){w1.x,w1.y},(v2f){w1.z,w1.w},
                           (v2f){w2.x,w2.y},(v2f){w2.z,w2.w},
                           (v2f){w3.x,w3.y},(v2f){w3.z,w3.w}};
        #pragma unroll
        for (int a=0;a<3;a++) {
          const v2f amv = (v2f){am[a][q], am[a][q]};
          #pragma unroll
          for (int p=0;p<8;p++) acc[a][p] += amv * wp[p];
        }
      }
    }
    // transposed store: WtT[col][j], lanes (jr) run along j -> coalesced
    float* wb = wsWt + (size_t)b*Nn*Mm;
    #pragma unroll
    for (int a=0;a<3;a++) {
      const int j = jr + 64*a;
      #pragma unroll
      for (int p=0;p<8;p++) {
        const int col = 16*kc + 2*p;
        wb[(size_t)(col    )*Mm + j] = acc[a][p].x;
        wb[(size_t)(col + 1)*Mm + j] = acc[a][p].y;
      }
    }
  }
  if (t < Nn) {
    float cc = 0.f;
    #pragma unroll 4
    for (int k=0;k<Nn;k++) cc += smem[k*Nn + t] * qb[k];
    wsC[(size_t)b*Nn + t] = cc;
  }
}

//======================= Kernel 2: row-sharing V-space ADMM loop ===================
#define WT_LD 196                       // padded WT row stride (floats)
#define S_SLOT 36                       // padded slot per 24-float s-chunk (bank-spread)
#define S_BUF  (8*S_SLOT)               // 288 floats per s buffer
#define OFF_S0   (Nn*WT_LD)             // 25088
#define OFF_S1   (OFF_S0 + S_BUF)       // 25376
#define OFF_SACC (OFF_S1 + S_BUF)       // 25664
#define OFF_C    (OFF_SACC + Mm)        // 25856
#define OFF_FLAG (OFF_C + Nn)           // 25984
#define LOOP_LDS_FLOATS (OFF_FLAG + 2)  // 25986 floats = 103944 B

// 512 thr = 8 waves = 2/SIMD even. Per-lane: Ve 72 + state ~40 + temps ~40
// ~= 150 VGPR < 256 budget at 2 waves/EU -> no spill.
__global__ __launch_bounds__(512, 2) void
loop_kernel(const float* __restrict__ Ag, const float* __restrict__ lg,
            const float* __restrict__ ug, const float* __restrict__ wsWtT,
            const float* __restrict__ wsC, float* __restrict__ outg)
{
  extern __shared__ float smem[];
  const int t = threadIdx.x, b = blockIdx.x;
  // eighth e on lane bits {0,1,3}; row-slot rw on bits {2,4,5}; wave = t>>6
  const int e  = (t & 3) | ((t >> 1) & 4);            // 0..7
  const int rw = ((t >> 2) & 1) | ((t >> 3) & 6);     // 0..7
  const int j0 = ((t >> 6) << 3) | rw;                // 0..63; rows j0,+64,+128
  const float* __restrict__ Wg = wsWtT + (size_t)b*Nn*Mm;   // [128][192]
  const float* __restrict__ cb = wsC  + (size_t)b*Nn;
  const float* __restrict__ Ab = Ag   + (size_t)b*Mm*Nn;

  float* WT    = smem;                 // [128][196]
  float* sT0   = smem + OFF_S0;        // padded: row j at 36*(j/24) + j%24
  float* sT1   = smem + OFF_S1;
  float* sacc  = smem + OFF_SACC;      // plain [192]
  float* c_s   = smem + OFF_C;
  float* sflag = smem + OFF_FLAG;

  // ---- stage WtT into LDS: wave w covers rows k=kb*8+w, 64-float col segments
  for (int kb = 0; kb < 16; kb++) {
    const int k  = (kb << 3) | (t >> 6);
    const int jc = t & 63;
    WT[k*WT_LD + jc]       = Wg[(size_t)k*Mm + jc];
    WT[k*WT_LD + 64 + jc]  = Wg[(size_t)k*Mm + 64 + jc];
    WT[k*WT_LD + 128 + jc] = Wg[(size_t)k*Mm + 128 + jc];
  }
  if (t < Nn) c_s[t] = cb[t];
  if (t < S_BUF) sT0[t] = 0.f;
  if (t < 2) sflag[t] = 0.f;
  __syncthreads();

  // ---- per-lane row pointers, bounds ----
  const float* A0 = Ab + (size_t)j0*Nn;
  const float* A1 = A0 + (size_t)64*Nn;
  const float* A2 = A0 + (size_t)128*Nn;
  float lreg[3], ureg[3];
  lreg[0] = lg[(size_t)b*Mm + j0];       ureg[0] = ug[(size_t)b*Mm + j0];
  lreg[1] = lg[(size_t)b*Mm + j0 + 64];  ureg[1] = ug[(size_t)b*Mm + j0 + 64];
  lreg[2] = lg[(size_t)b*Mm + j0 + 128]; ureg[2] = ug[(size_t)b*Mm + j0 + 128];

  // ---- d = A_j . c  (eighth partial over k in [16e,16e+16), dpp-combined) ----
  float dr[3];
  {
    const float4* cr = (const float4*)(c_s + 16*e);
    const float4 c0 = cr[0], c1 = cr[1], c2 = cr[2], c3 = cr[3];
    const float* Aj[3] = {A0, A1, A2};
    #pragma unroll
    for (int a = 0; a < 3; a++) {
      const float4* ar = (const float4*)(Aj[a] + 16*e);
      const float4 a0 = ar[0], a1 = ar[1], a2 = ar[2], a3 = ar[3];
      float dp = a0.x*c0.x + a0.y*c0.y + a0.z*c0.z + a0.w*c0.w
               + a1.x*c1.x + a1.y*c1.y + a1.z*c1.z + a1.w*c1.w
               + a2.x*c2.x + a2.y*c2.y + a2.z*c2.z + a2.w*c2.w
               + a3.x*c3.x + a3.y*c3.y + a3.z*c3.z + a3.w*c3.w;
      dp = dpp_add<0xB1>(dp);    // xor-1 (quad)
      dp = dpp_add<0x4E>(dp);    // xor-2 (quad)
      dp = dpp_add<0x128>(dp);   // xor-8 (row_ror:8)
      dr[a] = dp;
    }
  }

  // ---- V eighth for 3 rows: Ve[a][p] = V[j0+64a][24e+2p .. +2) ----
  v2f Ve[3][12];
  #pragma unroll
  for (int a = 0; a < 3; a++)
    #pragma unroll
    for (int p = 0; p < 12; p++) Ve[a][p] = (v2f){0.f, 0.f};
  for (int k4 = 0; k4 < 32; k4++) {
    const v4f a4_0 = *(const v4f*)&A0[4*k4];
    const v4f a4_1 = *(const v4f*)&A1[4*k4];
    const v4f a4_2 = *(const v4f*)&A2[4*k4];
    #pragma unroll
    for (int kk = 0; kk < 4; kk++) {
      const float* wp = &WT[(4*k4 + kk)*WT_LD + 24*e];
      const v4f w0 = *(const v4f*)&wp[0];
      const v4f w1 = *(const v4f*)&wp[4];
      const v4f w2 = *(const v4f*)&wp[8];
      const v4f w3 = *(const v4f*)&wp[12];
      const v4f w4 = *(const v4f*)&wp[16];
      const v4f w5 = *(const v4f*)&wp[20];
      const v2f wv[12] = {(v2f){w0.x,w0.y},(v2f){w0.z,w0.w},
                          (v2f){w1.x,w1.y},(v2f){w1.z,w1.w},
                          (v2f){w2.x,w2.y},(v2f){w2.z,w2.w},
                          (v2f){w3.x,w3.y},(v2f){w3.z,w3.w},
                          (v2f){w4.x,w4.y},(v2f){w4.z,w4.w},
                          (v2f){w5.x,w5.y},(v2f){w5.z,w5.w}};
      const float ax0 = a4_0[kk], ax1 = a4_1[kk], ax2 = a4_2[kk];
      const v2f av0 = (v2f){ax0, ax0};
      const v2f av1 = (v2f){ax1, ax1};
      const v2f av2 = (v2f){ax2, ax2};
      #pragma unroll
      for (int p = 0; p < 12; p++) {
        Ve[0][p] = __builtin_elementwise_fma(av0, wv[p], Ve[0][p]);
        Ve[1][p] = __builtin_elementwise_fma(av1, wv[p], Ve[1][p]);
        Ve[2][p] = __builtin_elementwise_fma(av2, wv[p], Ve[2][p]);
      }
    }
  }

  // ---- iteration state ----
  float sreg[3] = {0.f, 0.f, 0.f};
  float preg[3] = {0.f, 0.f, 0.f};
  float Sacc[3] = {0.f, 0.f, 0.f};
  bool cvg = false;
  // write slot for this lane (lane e<3 writes row j0+64e); padded address
  const int jsel = j0 + 64*e;                         // valid when e<3
  const int wsel = S_SLOT*(jsel/24) + (jsel%24);
  const bool wr_act = (e < 3);
  const float* rbase0 = sT0 + S_SLOT*e;
  const float* rbase1 = sT1 + S_SLOT*e;

#define ITER(RP, WR, CHK, PH)                                                  \
  {                                                                            \
    const v4f s0 = *(const v4f*)&(RP)[0];                                      \
    const v4f s1 = *(const v4f*)&(RP)[4];                                      \
    const v4f s2 = *(const v4f*)&(RP)[8];                                      \
    const v4f s3 = *(const v4f*)&(RP)[12];                                     \
    const v4f s4 = *(const v4f*)&(RP)[16];                                     \
    const v4f s5 = *(const v4f*)&(RP)[20];                                     \
    const v2f sv[12] = {(v2f){s0.x,s0.y},(v2f){s0.z,s0.w},                     \
                        (v2f){s1.x,s1.y},(v2f){s1.z,s1.w},                     \
                        (v2f){s2.x,s2.y},(v2f){s2.z,s2.w},                     \
                        (v2f){s3.x,s3.y},(v2f){s3.z,s3.w},                     \
                        (v2f){s4.x,s4.y},(v2f){s4.z,s4.w},                     \
                        (v2f){s5.x,s5.y},(v2f){s5.z,s5.w}};                    \
    v2f x0[3], x1[3];                                                          \
    _Pragma("unroll")                                                          \
    for (int a = 0; a < 3; a++) { x0[a]=(v2f){0.f,0.f}; x1[a]=(v2f){0.f,0.f}; }\
    _Pragma("unroll")                                                          \
    for (int p = 0; p < 6; p++) {                                              \
      _Pragma("unroll")                                                        \
      for (int a = 0; a < 3; a++) {                                            \
        x0[a] = __builtin_elementwise_fma(Ve[a][2*p],   sv[2*p],   x0[a]);     \
        x1[a] = __builtin_elementwise_fma(Ve[a][2*p+1], sv[2*p+1], x1[a]);     \
      }                                                                        \
    }                                                                          \
    float sn[3], pn[3];                                                        \
    _Pragma("unroll")                                                          \
    for (int a = 0; a < 3; a++) {                                              \
      const v2f xs = x0[a] + x1[a];                                            \
      float pr = xs.x + xs.y;                                                  \
      pr = dpp_add<0xB1>(pr);                                                  \
      pr = dpp_add<0x4E>(pr);                                                  \
      pr = dpp_add<0x128>(pr);                                                 \
      const float w_ = pr - dr[a];                                             \
      const float v_ = fmaf(ALPHA_, w_, preg[a]);                              \
      const float z_ = __builtin_amdgcn_fmed3f(v_, lreg[a], ureg[a]);          \
      sn[a] = RHO_ * fmaf(2.0f, z_, -v_);                                      \
      pn[a] = fmaf(-ALPHA_, z_, v_);                                           \
    }                                                                          \
    const float vsel = (e == 1) ? sn[1] : ((e == 2) ? sn[2] : sn[0]);          \
    if (wr_act) (WR)[wsel] = vsel;                                             \
    if (CHK) {                                                                 \
      if (!(sn[0]==sreg[0] && pn[0]==preg[0] &&                                \
            sn[1]==sreg[1] && pn[1]==preg[1] &&                                \
            sn[2]==sreg[2] && pn[2]==preg[2])) sflag[PH] = 1.f;                \
    }                                                                          \
    _Pragma("unroll")                                                          \
    for (int a = 0; a < 3; a++) {                                              \
      Sacc[a] = fmaf(1.0f - ALPHA_, Sacc[a], ALPHA_ * sreg[a]);                \
      sreg[a] = sn[a]; preg[a] = pn[a];                                        \
    }                                                                          \
    if ((CHK) && t == 0) sflag[(PH) ^ 1] = 0.f;                                \
    __syncthreads();                                                           \
    if (CHK) cvg = (sflag[PH] == 0.f);                                         \
  }

  #pragma unroll 1
  for (int it2 = 0; it2 < NITERS_/2; it2++) {
    ITER(rbase0, sT1, false, 0)
    const bool chk = ((it2 & 3) == 3) && (it2 < NITERS_/2 - 40);
    const int ph = (it2 >> 2) & 1;
    ITER(rbase1, sT0, chk, ph)
    if (cvg) break;   // bitwise fixed point: remaining iterations are identities
  }
#undef ITER
  if (cvg) {
    #pragma unroll
    for (int a = 0; a < 3; a++) Sacc[a] = sreg[a];  // Sacc -> s* ; |(-0.6)^80|~2e-18
  }

  // ---- epilogue: x = Wt^T Sacc - c  (= WtT rows . Sacc) ----
  if (wr_act) {
    const float ssel = (e == 1) ? Sacc[1] : ((e == 2) ? Sacc[2] : Sacc[0]);
    sacc[jsel] = ssel;
  }
  __syncthreads();
  if (t < Nn) {
    const float* wr = &WT[t*WT_LD];
    v2f xa = (v2f){0.f,0.f}, xb = (v2f){0.f,0.f};
    #pragma unroll
    for (int j4 = 0; j4 < 48; j4++) {
      const v4f wv = *(const v4f*)&wr[4*j4];
      const v4f sv = *(const v4f*)&sacc[4*j4];
      xa = __builtin_elementwise_fma((v2f){wv.x,wv.y}, (v2f){sv.x,sv.y}, xa);
      xb = __builtin_elementwise_fma((v2f){wv.z,wv.w}, (v2f){sv.z,sv.w}, xb);
    }
    xa += xb;
    outg[(size_t)b*Nn + t] = xa.x + xa.y - c_s[t];
  }
}

extern "C" void kernel_launch(void* const* d_in, const int* in_sizes, int n_in,
                              void* d_out, int out_size, void* d_ws, size_t ws_size,
                              hipStream_t stream) {
  const float* P = (const float*)d_in[0];
  const float* q = (const float*)d_in[1];
  const float* A = (const float*)d_in[2];
  const float* l = (const float*)d_in[3];
  const float* u = (const float*)d_in[4];
  (void)in_sizes; (void)n_in; (void)out_size; (void)ws_size;
  float* wsWt = (float*)d_ws;                      // WtT: 256*128*192 floats = 25.2 MB
  float* wsC  = wsWt + (size_t)256*Mm*Nn;          // 256*128 floats
  precompute_kernel<<<256, 512, 0, stream>>>(P, q, A, wsWt, wsC);
  loop_kernel<<<256, 512, LOOP_LDS_FLOATS*4, stream>>>(A, l, u, wsWt, wsC, (float*)d_out);
}